// Round 4
// baseline (235.130 us; speedup 1.0000x reference)
//
#include <hip/hip_runtime.h>

#define HW  16384
#define WD  128

__device__ __forceinline__ unsigned short f2bf(float f) {
    unsigned int u = __builtin_bit_cast(unsigned int, f);
    u += 0x7FFFu + ((u >> 16) & 1u);          // RNE
    return (unsigned short)(u >> 16);
}
__device__ __forceinline__ float bf2f(unsigned int s) {
    return __builtin_bit_cast(float, (s & 0xFFFFu) << 16);
}
__device__ __forceinline__ float ftanh(float v) {
    const float e = __expf(2.0f * v);
    return 1.0f - __fdividef(2.0f, e + 1.0f);
}

// ---- la_pre: pointwise, channel-split for TLP. z = p*3 + q:
//   q<2 : 16 Wv rows -> 2 bf16 uint4 planes      (512 FMA)
//   q==2: conv1+bn1+tanh+conv2 -> nb/mask planes (336 FMA)
// No redundant FLOPs; x slab is read by 3 blocks (L3-resident).
__global__ __launch_bounds__(256, 8) void la_pre(
    const float* __restrict__ x,
    const float* __restrict__ w1, const float* __restrict__ b1,
    const float* __restrict__ g1, const float* __restrict__ be1,
    const float* __restrict__ m1, const float* __restrict__ v1,
    const float* __restrict__ w2, const float* __restrict__ b2,
    const float* __restrict__ g2, const float* __restrict__ be2,
    const float* __restrict__ m2, const float* __restrict__ v2,
    const float* __restrict__ wv,
    uint4* __restrict__ v4, float* __restrict__ nb, float* __restrict__ mask)
{
    const int pix = blockIdx.x * blockDim.x + threadIdx.x;   // 0..16383
    const int b   = blockIdx.y;
    const int z   = blockIdx.z;                              // 0..23
    const int p   = z / 3;                                   // t-group
    const int q   = z - 3 * p;                               // sub-task

    const float* xp = x + (size_t)(b * 256 + p * 32) * HW + pix;
    float xv[32];
#pragma unroll
    for (int c = 0; c < 32; ++c) xv[c] = xp[(size_t)c * HW];

    if (q < 2) {
        // ---- Wv rows q*16 .. q*16+15 -> planes (b*8+p)*4 + q*2 + {0,1} ----
        const float* wvp = wv + p * 1024 + q * 512;
#pragma unroll
        for (int c8 = 0; c8 < 2; ++c8) {
            float ov[8];
#pragma unroll
            for (int j = 0; j < 8; ++j) {
                float a = 0.f;
#pragma unroll
                for (int ci = 0; ci < 32; ++ci)
                    a = fmaf(xv[ci], wvp[(c8 * 8 + j) * 32 + ci], a);
                ov[j] = a;
            }
            uint4 u;
            u.x = (unsigned)f2bf(ov[0]) | ((unsigned)f2bf(ov[1]) << 16);
            u.y = (unsigned)f2bf(ov[2]) | ((unsigned)f2bf(ov[3]) << 16);
            u.z = (unsigned)f2bf(ov[4]) | ((unsigned)f2bf(ov[5]) << 16);
            u.w = (unsigned)f2bf(ov[6]) | ((unsigned)f2bf(ov[7]) << 16);
            v4[((size_t)((b * 8 + p) * 4) + q * 2 + c8) * HW + pix] = u;
        }
    } else {
        // ---- conv1 + bn1 + tanh ----
        const float* w1g = w1 + p * 256;
        float tv[8];
#pragma unroll
        for (int o = 0; o < 8; ++o) {
            float a = 0.f;
#pragma unroll
            for (int ci = 0; ci < 32; ++ci)
                a = fmaf(xv[ci], w1g[o * 32 + ci], a);
            const int ch = p * 8 + o;
            const float inv = g1[ch] * rsqrtf(v1[ch] + 1e-5f);
            const float add = be1[ch] + (b1[ch] - m1[ch]) * inv;
            tv[o] = ftanh(fmaf(a, inv, add));
        }
        // ---- conv2 rows 0..9 + bn2 -> nb (c<8) / mask (c>=8) ----
#pragma unroll
        for (int o = 0; o < 10; ++o) {
            const int c = p * 10 + o;             // global mn channel (uniform)
            float a = 0.f;
#pragma unroll
            for (int i = 0; i < 8; ++i)
                a = fmaf(tv[i], w2[p * 80 + o * 8 + i], a);
            const float inv = g2[c] * rsqrtf(v2[c] + 1e-5f);
            const float add = be2[c] + (b2[c] - m2[c]) * inv;
            const float val = fmaf(a, inv, add);
            if (c < 8) {                          // neighbor plane (p==0 only)
                nb[(size_t)(b * 8 + c) * HW + pix] = val;
            } else {                              // mask plane [b][g][k]
                const int gk = c - 8, g = gk / 9, k = gk - 9 * g;
                mask[((size_t)(b * 8 + g) * 9 + k) * HW + pix] = val;
            }
        }
    }
}

// ---- la_attn: LDS-free streaming stencil, half-channel split for TLP.
//   y = bg*2 + h: this block produces out channels g*32 + h*16 .. +15
//   from v planes 2h, 2h+1. Logits recomputed per half (cache-hot).
__global__ __launch_bounds__(256, 8) void la_attn(
    const uint4* __restrict__ v4, const float* __restrict__ nb,
    const float* __restrict__ mask, float* __restrict__ out)
{
    const int pix = blockIdx.x * blockDim.x + threadIdx.x;   // 0..16383
    const int y   = blockIdx.y;                              // 0..31
    const int bg  = y >> 1, h = y & 1;
    const int b   = bg >> 3, g = bg & 7;
    const int iy  = pix >> 7, ix = pix & 127;

    const float* mp  = mask + ((size_t)(b * 8 + g) * 9) * HW + pix;
    const float* nbp = nb   + (size_t)(b * 8 + g) * HW + pix;
    const uint4* vg  = v4   + ((size_t)((b * 8 + g) * 4) + 2 * h) * HW + pix;

    // logits: mask at center (streamed once -> NT) + neighbor tap
    float lg[9];
    float mx = -1e30f;
#pragma unroll
    for (int k = 0; k < 9; ++k) {
        const int dy = k / 3 - 1, dx = k % 3 - 1;
        const bool ok = ((unsigned)(iy + dy) < 128u) && ((unsigned)(ix + dx) < 128u);
        const float nv = ok ? nbp[dy * WD + dx] : 0.f;
        lg[k] = __builtin_nontemporal_load(mp + (size_t)k * HW) + nv;
        mx = fmaxf(mx, lg[k]);
    }
    float ssum = 0.f;
#pragma unroll
    for (int k = 0; k < 9; ++k) { lg[k] = __expf(lg[k] - mx); ssum += lg[k]; }
    const float rs = 1.f / ssum;               // applied once at the store

    // s = sum_k e_k * v_tap over this half's 16 channels
    float s[16];
#pragma unroll
    for (int c = 0; c < 16; ++c) s[c] = 0.f;
#pragma unroll
    for (int k = 0; k < 9; ++k) {
        const int dy = k / 3 - 1, dx = k % 3 - 1;
        const bool ok = ((unsigned)(iy + dy) < 128u) && ((unsigned)(ix + dx) < 128u);
        if (ok) {                                 // divergent only in edge waves
            const int off = dy * WD + dx;
            const float e = lg[k];
#pragma unroll
            for (int c8 = 0; c8 < 2; ++c8) {
                const uint4 u = vg[(size_t)c8 * HW + off];
                s[c8 * 8 + 0] = fmaf(e, bf2f(u.x),       s[c8 * 8 + 0]);
                s[c8 * 8 + 1] = fmaf(e, bf2f(u.x >> 16), s[c8 * 8 + 1]);
                s[c8 * 8 + 2] = fmaf(e, bf2f(u.y),       s[c8 * 8 + 2]);
                s[c8 * 8 + 3] = fmaf(e, bf2f(u.y >> 16), s[c8 * 8 + 3]);
                s[c8 * 8 + 4] = fmaf(e, bf2f(u.z),       s[c8 * 8 + 4]);
                s[c8 * 8 + 5] = fmaf(e, bf2f(u.z >> 16), s[c8 * 8 + 5]);
                s[c8 * 8 + 6] = fmaf(e, bf2f(u.w),       s[c8 * 8 + 6]);
                s[c8 * 8 + 7] = fmaf(e, bf2f(u.w >> 16), s[c8 * 8 + 7]);
            }
        }
    }

    float* og = out + (size_t)(b * 256 + g * 32 + h * 16) * HW + pix;
#pragma unroll 8
    for (int o = 0; o < 16; ++o)
        __builtin_nontemporal_store(s[o] * rs, og + (size_t)o * HW);
}

extern "C" void kernel_launch(void* const* d_in, const int* in_sizes, int n_in,
                              void* d_out, int out_size, void* d_ws, size_t ws_size,
                              hipStream_t stream)
{
    const float* x   = (const float*)d_in[0];
    const float* w1  = (const float*)d_in[1];
    const float* b1  = (const float*)d_in[2];
    const float* g1  = (const float*)d_in[3];
    const float* be1 = (const float*)d_in[4];
    const float* m1  = (const float*)d_in[5];
    const float* v1  = (const float*)d_in[6];
    const float* w2  = (const float*)d_in[7];
    const float* b2  = (const float*)d_in[8];
    const float* g2  = (const float*)d_in[9];
    const float* be2 = (const float*)d_in[10];
    const float* m2  = (const float*)d_in[11];
    const float* v2  = (const float*)d_in[12];
    const float* wv  = (const float*)d_in[13];

    float* out = (float*)d_out;

    // workspace: v (bf16, 64 uint4-planes, 16.8 MB) | nb (fp32, 1 MB) | mask (fp32, 9.4 MB)
    uint4* v4  = (uint4*)d_ws;
    float* nbw = (float*)((char*)d_ws + (size_t)64 * HW * 16);
    float* msk = nbw + (size_t)16 * HW;

    dim3 blk(256);
    dim3 gpre(HW / 256, 2, 24);    // 3072 blocks: px x b x (p*3+q)
    dim3 gatt(HW / 256, 32);       // 2048 blocks: px x (b,g,half)

    hipLaunchKernelGGL(la_pre, gpre, blk, 0, stream,
                       x, w1, b1, g1, be1, m1, v1, w2, b2, g2, be2, m2, v2,
                       wv, v4, nbw, msk);
    hipLaunchKernelGGL(la_attn, gatt, blk, 0, stream,
                       v4, nbw, msk, out);
}

// Round 5
// 138.817 us; speedup vs baseline: 1.6938x; 1.6938x over previous
//
#include <hip/hip_runtime.h>

#define HW  16384
#define WD  128

__device__ __forceinline__ unsigned short f2bf(float f) {
    unsigned int u = __builtin_bit_cast(unsigned int, f);
    u += 0x7FFFu + ((u >> 16) & 1u);          // RNE
    return (unsigned short)(u >> 16);
}
__device__ __forceinline__ float bf2f(unsigned int s) {
    return __builtin_bit_cast(float, (s & 0xFFFFu) << 16);
}
__device__ __forceinline__ float ftanh(float v) {
    const float e = __expf(2.0f * v);
    return 1.0f - __fdividef(2.0f, e + 1.0f);
}

// ---- la_pre: pointwise, channel-split for TLP. z = p*3 + q:
//   q<2 : 16 Wv rows -> 2 bf16 uint4 planes      (512 FMA)
//   q==2: conv1+bn1+tanh+conv2 -> nb/mask planes (336 FMA)
// No redundant FLOPs; x slab is read by 3 blocks (L3-resident).
// NOTE: plain launch_bounds(256) — R4's (256,8) forced VGPR=32 and spilled
// xv[32] to scratch (FETCH 157MB/WRITE 215MB). Actual ~56 VGPR already
// allows 8 waves/SIMD; occupancy comes from the 3072-block grid.
__global__ __launch_bounds__(256) void la_pre(
    const float* __restrict__ x,
    const float* __restrict__ w1, const float* __restrict__ b1,
    const float* __restrict__ g1, const float* __restrict__ be1,
    const float* __restrict__ m1, const float* __restrict__ v1,
    const float* __restrict__ w2, const float* __restrict__ b2,
    const float* __restrict__ g2, const float* __restrict__ be2,
    const float* __restrict__ m2, const float* __restrict__ v2,
    const float* __restrict__ wv,
    uint4* __restrict__ v4, float* __restrict__ nb, float* __restrict__ mask)
{
    const int pix = blockIdx.x * blockDim.x + threadIdx.x;   // 0..16383
    const int b   = blockIdx.y;
    const int z   = blockIdx.z;                              // 0..23
    const int p   = z / 3;                                   // t-group
    const int q   = z - 3 * p;                               // sub-task

    const float* xp = x + (size_t)(b * 256 + p * 32) * HW + pix;
    float xv[32];
#pragma unroll
    for (int c = 0; c < 32; ++c) xv[c] = xp[(size_t)c * HW];

    if (q < 2) {
        // ---- Wv rows q*16 .. q*16+15 -> planes (b*8+p)*4 + q*2 + {0,1} ----
        const float* wvp = wv + p * 1024 + q * 512;
#pragma unroll
        for (int c8 = 0; c8 < 2; ++c8) {
            float ov[8];
#pragma unroll
            for (int j = 0; j < 8; ++j) {
                float a = 0.f;
#pragma unroll
                for (int ci = 0; ci < 32; ++ci)
                    a = fmaf(xv[ci], wvp[(c8 * 8 + j) * 32 + ci], a);
                ov[j] = a;
            }
            uint4 u;
            u.x = (unsigned)f2bf(ov[0]) | ((unsigned)f2bf(ov[1]) << 16);
            u.y = (unsigned)f2bf(ov[2]) | ((unsigned)f2bf(ov[3]) << 16);
            u.z = (unsigned)f2bf(ov[4]) | ((unsigned)f2bf(ov[5]) << 16);
            u.w = (unsigned)f2bf(ov[6]) | ((unsigned)f2bf(ov[7]) << 16);
            v4[((size_t)((b * 8 + p) * 4) + q * 2 + c8) * HW + pix] = u;
        }
    } else {
        // ---- conv1 + bn1 + tanh ----
        const float* w1g = w1 + p * 256;
        float tv[8];
#pragma unroll
        for (int o = 0; o < 8; ++o) {
            float a = 0.f;
#pragma unroll
            for (int ci = 0; ci < 32; ++ci)
                a = fmaf(xv[ci], w1g[o * 32 + ci], a);
            const int ch = p * 8 + o;
            const float inv = g1[ch] * rsqrtf(v1[ch] + 1e-5f);
            const float add = be1[ch] + (b1[ch] - m1[ch]) * inv;
            tv[o] = ftanh(fmaf(a, inv, add));
        }
        // ---- conv2 rows 0..9 + bn2 -> nb (c<8) / mask (c>=8) ----
#pragma unroll
        for (int o = 0; o < 10; ++o) {
            const int c = p * 10 + o;             // global mn channel (uniform)
            float a = 0.f;
#pragma unroll
            for (int i = 0; i < 8; ++i)
                a = fmaf(tv[i], w2[p * 80 + o * 8 + i], a);
            const float inv = g2[c] * rsqrtf(v2[c] + 1e-5f);
            const float add = be2[c] + (b2[c] - m2[c]) * inv;
            const float val = fmaf(a, inv, add);
            if (c < 8) {                          // neighbor plane (p==0 only)
                nb[(size_t)(b * 8 + c) * HW + pix] = val;
            } else {                              // mask plane [b][g][k]
                const int gk = c - 8, g = gk / 9, k = gk - 9 * g;
                mask[((size_t)(b * 8 + g) * 9 + k) * HW + pix] = val;
            }
        }
    }
}

// ---- la_attn: LDS-free streaming stencil, half-channel split for TLP.
//   y = bg*2 + h: this block produces out channels g*32 + h*16 .. +15
//   from v planes 2h, 2h+1. Logits recomputed per half (cache-hot).
__global__ __launch_bounds__(256) void la_attn(
    const uint4* __restrict__ v4, const float* __restrict__ nb,
    const float* __restrict__ mask, float* __restrict__ out)
{
    const int pix = blockIdx.x * blockDim.x + threadIdx.x;   // 0..16383
    const int y   = blockIdx.y;                              // 0..31
    const int bg  = y >> 1, h = y & 1;
    const int b   = bg >> 3, g = bg & 7;
    const int iy  = pix >> 7, ix = pix & 127;

    const float* mp  = mask + ((size_t)(b * 8 + g) * 9) * HW + pix;
    const float* nbp = nb   + (size_t)(b * 8 + g) * HW + pix;
    const uint4* vg  = v4   + ((size_t)((b * 8 + g) * 4) + 2 * h) * HW + pix;

    // logits: mask at center + neighbor tap (zero-padded OOB)
    float lg[9];
    float mx = -1e30f;
#pragma unroll
    for (int k = 0; k < 9; ++k) {
        const int dy = k / 3 - 1, dx = k % 3 - 1;
        const bool ok = ((unsigned)(iy + dy) < 128u) && ((unsigned)(ix + dx) < 128u);
        const float nv = ok ? nbp[dy * WD + dx] : 0.f;
        lg[k] = mp[(size_t)k * HW] + nv;
        mx = fmaxf(mx, lg[k]);
    }
    float ssum = 0.f;
#pragma unroll
    for (int k = 0; k < 9; ++k) { lg[k] = __expf(lg[k] - mx); ssum += lg[k]; }
    const float rs = 1.f / ssum;               // applied once at the store

    // s = sum_k e_k * v_tap over this half's 16 channels
    float s[16];
#pragma unroll
    for (int c = 0; c < 16; ++c) s[c] = 0.f;
#pragma unroll
    for (int k = 0; k < 9; ++k) {
        const int dy = k / 3 - 1, dx = k % 3 - 1;
        const bool ok = ((unsigned)(iy + dy) < 128u) && ((unsigned)(ix + dx) < 128u);
        if (ok) {                                 // divergent only in edge waves
            const int off = dy * WD + dx;
            const float e = lg[k];
#pragma unroll
            for (int c8 = 0; c8 < 2; ++c8) {
                const uint4 u = vg[(size_t)c8 * HW + off];
                s[c8 * 8 + 0] = fmaf(e, bf2f(u.x),       s[c8 * 8 + 0]);
                s[c8 * 8 + 1] = fmaf(e, bf2f(u.x >> 16), s[c8 * 8 + 1]);
                s[c8 * 8 + 2] = fmaf(e, bf2f(u.y),       s[c8 * 8 + 2]);
                s[c8 * 8 + 3] = fmaf(e, bf2f(u.y >> 16), s[c8 * 8 + 3]);
                s[c8 * 8 + 4] = fmaf(e, bf2f(u.z),       s[c8 * 8 + 4]);
                s[c8 * 8 + 5] = fmaf(e, bf2f(u.z >> 16), s[c8 * 8 + 5]);
                s[c8 * 8 + 6] = fmaf(e, bf2f(u.w),       s[c8 * 8 + 6]);
                s[c8 * 8 + 7] = fmaf(e, bf2f(u.w >> 16), s[c8 * 8 + 7]);
            }
        }
    }

    float* og = out + (size_t)(b * 256 + g * 32 + h * 16) * HW + pix;
#pragma unroll 8
    for (int o = 0; o < 16; ++o)
        __builtin_nontemporal_store(s[o] * rs, og + (size_t)o * HW);
}

extern "C" void kernel_launch(void* const* d_in, const int* in_sizes, int n_in,
                              void* d_out, int out_size, void* d_ws, size_t ws_size,
                              hipStream_t stream)
{
    const float* x   = (const float*)d_in[0];
    const float* w1  = (const float*)d_in[1];
    const float* b1  = (const float*)d_in[2];
    const float* g1  = (const float*)d_in[3];
    const float* be1 = (const float*)d_in[4];
    const float* m1  = (const float*)d_in[5];
    const float* v1  = (const float*)d_in[6];
    const float* w2  = (const float*)d_in[7];
    const float* b2  = (const float*)d_in[8];
    const float* g2  = (const float*)d_in[9];
    const float* be2 = (const float*)d_in[10];
    const float* m2  = (const float*)d_in[11];
    const float* v2  = (const float*)d_in[12];
    const float* wv  = (const float*)d_in[13];

    float* out = (float*)d_out;

    // workspace: v (bf16, 64 uint4-planes, 16.8 MB) | nb (fp32, 1 MB) | mask (fp32, 9.4 MB)
    uint4* v4  = (uint4*)d_ws;
    float* nbw = (float*)((char*)d_ws + (size_t)64 * HW * 16);
    float* msk = nbw + (size_t)16 * HW;

    dim3 blk(256);
    dim3 gpre(HW / 256, 2, 24);    // 3072 blocks: px x b x (p*3+q)
    dim3 gatt(HW / 256, 32);       // 2048 blocks: px x (b,g,half)

    hipLaunchKernelGGL(la_pre, gpre, blk, 0, stream,
                       x, w1, b1, g1, be1, m1, v1, w2, b2, g2, be2, m2, v2,
                       wv, v4, nbw, msk);
    hipLaunchKernelGGL(la_attn, gatt, blk, 0, stream,
                       v4, nbw, msk, out);
}